// Round 1
// baseline (481.825 us; speedup 1.0000x reference)
//
#include <hip/hip_runtime.h>
#include <hip/hip_bf16.h>

// B=32, L=512, D=512, K=3. T derived from out_size.
// ws layout: xx (B*L*D f32, 33.5MB) | ranges (B*L f32) | means (B*L f32)

#define NB 32
#define NL 512
#define ND 512

// ---------------- Stage 1: fused convs + xx + ranges ----------------
__global__ __launch_bounds__(256) void fuse_kernel(
    const float* __restrict__ x,
    const float* __restrict__ df,
    const float* __restrict__ en,
    const float* __restrict__ pi,
    const int*   __restrict__ lens,
    const float* __restrict__ w_dur, const float* __restrict__ b_dur,
    const float* __restrict__ w_en,  const float* __restrict__ b_en,
    const float* __restrict__ w_pi,  const float* __restrict__ b_pi,
    const float* __restrict__ w_lin, const float* __restrict__ b_lin,
    float* __restrict__ xx, float* __restrict__ ranges)
{
    const int bl = blockIdx.x;            // b*NL + l
    const int b  = bl >> 9;
    const int l  = bl & (NL - 1);
    const int tid = threadIdx.x;

    // conv1d inputs (scalar per row, zero-padded)
    const float dm1 = (l > 0)      ? df[bl - 1] : 0.f;
    const float d0  = df[bl];
    const float dp1 = (l < NL - 1) ? df[bl + 1] : 0.f;
    const float em1 = (l > 0)      ? en[bl - 1] : 0.f;
    const float e0  = en[bl];
    const float ep1 = (l < NL - 1) ? en[bl + 1] : 0.f;
    const float pm1 = (l > 0)      ? pi[bl - 1] : 0.f;
    const float p0  = pi[bl];
    const float pp1 = (l < NL - 1) ? pi[bl + 1] : 0.f;

    float acc = 0.f;
    #pragma unroll
    for (int d = tid; d < ND; d += 256) {
        const float xv = x[(size_t)bl * ND + d];
        const float ev = w_en[d*3]*em1 + w_en[d*3+1]*e0 + w_en[d*3+2]*ep1 + b_en[d];
        const float pv = w_pi[d*3]*pm1 + w_pi[d*3+1]*p0 + w_pi[d*3+2]*pp1 + b_pi[d];
        const float xxv = xv + ev + pv;
        xx[(size_t)bl * ND + d] = xxv;
        const float dv = w_dur[d*3]*dm1 + w_dur[d*3+1]*d0 + w_dur[d*3+2]*dp1 + b_dur[d];
        acc += (xxv + dv) * w_lin[d];
    }

    // block reduce (wave64 shuffle + LDS)
    #pragma unroll
    for (int off = 32; off; off >>= 1) acc += __shfl_down(acc, off, 64);
    __shared__ float red[4];
    const int lane = tid & 63, wid = tid >> 6;
    if (lane == 0) red[wid] = acc;
    __syncthreads();
    if (tid == 0) {
        const float s = red[0] + red[1] + red[2] + red[3] + b_lin[0];
        // softplus = max(s,0) + log1p(exp(-|s|))
        float r = fmaxf(s, 0.f) + log1pf(expf(-fabsf(s)));
        if (l >= lens[b]) r = 1.0f;
        ranges[bl] = r;
    }
}

// ---------------- Stage 2: means via inclusive scan ----------------
__global__ __launch_bounds__(512) void means_kernel(
    const int* __restrict__ di, float* __restrict__ means)
{
    const int b = blockIdx.x;
    const int l = threadIdx.x;
    __shared__ int s[NL];
    const int d = di[b * NL + l];
    s[l] = d;
    __syncthreads();
    #pragma unroll
    for (int off = 1; off < NL; off <<= 1) {
        const int v = (l >= off) ? s[l - off] : 0;
        __syncthreads();
        s[l] += v;
        __syncthreads();
    }
    means[b * NL + l] = 0.5f * (float)d + (float)(s[l] - d);
}

// ---------------- Stage 3: weights (B,L,T) ----------------
__global__ __launch_bounds__(256) void weights_kernel(
    const float* __restrict__ ranges,
    const float* __restrict__ means,
    const int*   __restrict__ lens,
    float* __restrict__ weights, int T)
{
    const int b = blockIdx.y;
    const int t = blockIdx.x * 256 + threadIdx.x;
    __shared__ float sm[NL];    // means
    __shared__ float sinv[NL];  // 1/range
    __shared__ float sc[NL];    // coef = 0.39894.../range, 0 if invalid

    const int len = lens[b];
    for (int l = threadIdx.x; l < NL; l += 256) {
        const float r = ranges[b * NL + l];
        const float inv = 1.f / r;
        sm[l] = means[b * NL + l];
        sinv[l] = inv;
        sc[l] = (l < len) ? 0.3989422804014327f * inv : 0.f;
    }
    __syncthreads();

    if (t >= T) return;
    const float ft = (float)t + 0.5f;

    float sum = 0.f;
    #pragma unroll 4
    for (int l = 0; l < NL; ++l) {
        const float z = (ft - sm[l]) * sinv[l];
        sum += sc[l] * __expf(-0.5f * z * z);
    }
    const float dinv = 1.f / (sum + 1e-20f);

    #pragma unroll 4
    for (int l = 0; l < NL; ++l) {
        const float z = (ft - sm[l]) * sinv[l];
        const float w = sc[l] * __expf(-0.5f * z * z) * dinv;
        weights[((size_t)b * NL + l) * T + t] = w;
    }
}

// ---------------- Stage 4: einsum bld,blt->btd as per-batch GEMM ----------------
// out[t][d] = sum_l W[l][t] * X[l][d]
#define BM 64
#define BN 64
#define BK 16
__global__ __launch_bounds__(256) void gemm_kernel(
    const float* __restrict__ xx,
    const float* __restrict__ weights,
    float* __restrict__ out, int T)
{
    const int b  = blockIdx.z;
    const int t0 = blockIdx.y * BM;
    const int d0 = blockIdx.x * BN;
    const float* __restrict__ W = weights + (size_t)b * NL * T;  // [l][t]
    const float* __restrict__ X = xx + (size_t)b * NL * ND;      // [l][d]
    float* __restrict__ O = out + (size_t)b * T * ND;            // [t][d]

    __shared__ float As[BK][BM];  // l x t
    __shared__ float Bs[BK][BN];  // l x d

    const int tid = threadIdx.x;
    const int tx = tid & 15;      // d sub-tile
    const int ty = tid >> 4;      // t sub-tile
    const int lr = tid >> 4;      // load row (0..15)
    const int lc = (tid & 15) * 4;

    const bool full_t = (t0 + BM <= T);
    const bool vec_ok = full_t && ((T & 3) == 0);

    float acc[4][4] = {};

    for (int l0 = 0; l0 < NL; l0 += BK) {
        // W tile: [l0+lr][t0+lc..+3]
        if (vec_ok) {
            const float4 wv = *(const float4*)&W[(size_t)(l0 + lr) * T + t0 + lc];
            *(float4*)&As[lr][lc] = wv;
        } else {
            #pragma unroll
            for (int j = 0; j < 4; ++j) {
                const int tcol = t0 + lc + j;
                As[lr][lc + j] = (tcol < T) ? W[(size_t)(l0 + lr) * T + tcol] : 0.f;
            }
        }
        // X tile: [l0+lr][d0+lc..+3]
        const float4 xv = *(const float4*)&X[(size_t)(l0 + lr) * ND + d0 + lc];
        *(float4*)&Bs[lr][lc] = xv;
        __syncthreads();

        #pragma unroll
        for (int k = 0; k < BK; ++k) {
            float a[4], bb[4];
            *(float4*)a  = *(const float4*)&As[k][ty * 4];
            *(float4*)bb = *(const float4*)&Bs[k][tx * 4];
            #pragma unroll
            for (int i = 0; i < 4; ++i)
                #pragma unroll
                for (int j = 0; j < 4; ++j)
                    acc[i][j] += a[i] * bb[j];
        }
        __syncthreads();
    }

    #pragma unroll
    for (int i = 0; i < 4; ++i) {
        const int t = t0 + ty * 4 + i;
        if (t < T) {
            float4 v = make_float4(acc[i][0], acc[i][1], acc[i][2], acc[i][3]);
            *(float4*)&O[(size_t)t * ND + d0 + tx * 4] = v;
        }
    }
}

extern "C" void kernel_launch(void* const* d_in, const int* in_sizes, int n_in,
                              void* d_out, int out_size, void* d_ws, size_t ws_size,
                              hipStream_t stream) {
    const float* x     = (const float*)d_in[0];
    const float* df    = (const float*)d_in[1];
    const int*   di    = (const int*)  d_in[2];
    const float* en    = (const float*)d_in[3];
    const float* pi    = (const float*)d_in[4];
    const int*   lens  = (const int*)  d_in[5];
    const float* w_dur = (const float*)d_in[6];
    const float* b_dur = (const float*)d_in[7];
    const float* w_en  = (const float*)d_in[8];
    const float* b_en  = (const float*)d_in[9];
    const float* w_pi  = (const float*)d_in[10];
    const float* b_pi  = (const float*)d_in[11];
    const float* w_lin = (const float*)d_in[12];
    const float* b_lin = (const float*)d_in[13];

    const int B = NB, L = NL, D = ND;
    const int T = out_size / (B * (L + D));   // out = B*T*D + B*L*T

    float* xup     = (float*)d_out;                    // (B,T,D)
    float* weights = xup + (size_t)B * T * D;          // (B,L,T)

    float* xx     = (float*)d_ws;                      // (B,L,D)
    float* ranges = xx + (size_t)B * L * D;            // (B,L)
    float* means  = ranges + (size_t)B * L;            // (B,L)

    hipLaunchKernelGGL(fuse_kernel, dim3(B * L), dim3(256), 0, stream,
                       x, df, en, pi, lens, w_dur, b_dur, w_en, b_en,
                       w_pi, b_pi, w_lin, b_lin, xx, ranges);

    hipLaunchKernelGGL(means_kernel, dim3(B), dim3(512), 0, stream, di, means);

    dim3 gw((T + 255) / 256, B);
    hipLaunchKernelGGL(weights_kernel, gw, dim3(256), 0, stream,
                       ranges, means, lens, weights, T);

    dim3 gg(D / BN, (T + BM - 1) / BM, B);
    hipLaunchKernelGGL(gemm_kernel, gg, dim3(256), 0, stream,
                       xx, weights, xup, T);
}

// Round 2
// 167.479 us; speedup vs baseline: 2.8769x; 2.8769x over previous
//
#include <hip/hip_runtime.h>
#include <hip/hip_bf16.h>
#include <stdint.h>

#define NB 32
#define NL 512
#define ND 512

typedef __bf16 bf16x8 __attribute__((ext_vector_type(8)));
typedef float  f32x4  __attribute__((ext_vector_type(4)));

__device__ __forceinline__ unsigned short f2bf(float f) {
    uint32_t u = __float_as_uint(f);
    u = (u + 0x7fffu + ((u >> 16) & 1u)) >> 16;
    return (unsigned short)u;
}

// ============================================================================
// FAST PATH
// X' layout (per batch): [kk=l>>5][db=d>>4] subtiles of 512 bf16:
//   subtile chunk c=0..63 (16B) holds (k=(c>>4)*8+j, n=c&15): X[l=kk*32+k][d=db*16+n]
// W' layout (per batch): [kk=l>>5][mb=t>>4] subtiles, element W[l][t] at same scheme.
// Both match the mfma_f32_16x16x32_bf16 A/B lane layout exactly, so the GEMM
// stages with linear global_load_lds and reads fragments lane-linearly.
// ============================================================================

// ---- Stage 1: fused convs -> X' bf16 (fragment layout) + ranges ----
__global__ __launch_bounds__(256) void fuse2_kernel(
    const float* __restrict__ x, const float* __restrict__ df,
    const float* __restrict__ en, const float* __restrict__ pi,
    const int* __restrict__ lens,
    const float* __restrict__ w_dur, const float* __restrict__ b_dur,
    const float* __restrict__ w_en,  const float* __restrict__ b_en,
    const float* __restrict__ w_pi,  const float* __restrict__ b_pi,
    const float* __restrict__ w_lin, const float* __restrict__ b_lin,
    unsigned short* __restrict__ Xb, float* __restrict__ ranges)
{
    const int blk = blockIdx.x;          // B * 64
    const int b   = blk >> 6;
    const int lb  = (blk & 63) << 3;     // 8 consecutive l
    const int tid = threadIdx.x;
    const int d0  = tid << 1;            // 2 consecutive d

    float we[2][3], wp[2][3], wd[2][3], bev[2], bpv[2], bdv[2], wl[2];
    #pragma unroll
    for (int q = 0; q < 2; ++q) {
        const int d = d0 + q;
        #pragma unroll
        for (int k = 0; k < 3; ++k) {
            we[q][k] = w_en[d*3+k];
            wp[q][k] = w_pi[d*3+k];
            wd[q][k] = w_dur[d*3+k];
        }
        bev[q] = b_en[d]; bpv[q] = b_pi[d]; bdv[q] = b_dur[d]; wl[q] = w_lin[d];
    }

    float acc[8];
    #pragma unroll
    for (int i = 0; i < 8; ++i) acc[i] = 0.f;

    uint4 chunk[2];
    unsigned short* cu = (unsigned short*)chunk;

    #pragma unroll
    for (int li = 0; li < 8; ++li) {
        const int l  = lb + li;
        const int bl = (b << 9) + l;
        const float dm1 = (l > 0)      ? df[bl-1] : 0.f;
        const float dc  = df[bl];
        const float dp1 = (l < NL-1)   ? df[bl+1] : 0.f;
        const float em1 = (l > 0)      ? en[bl-1] : 0.f;
        const float ec  = en[bl];
        const float ep1 = (l < NL-1)   ? en[bl+1] : 0.f;
        const float pm1 = (l > 0)      ? pi[bl-1] : 0.f;
        const float pc  = pi[bl];
        const float pp1 = (l < NL-1)   ? pi[bl+1] : 0.f;
        const float2 xv = *(const float2*)&x[(size_t)bl * ND + d0];
        #pragma unroll
        for (int q = 0; q < 2; ++q) {
            const float ev  = we[q][0]*em1 + we[q][1]*ec + we[q][2]*ep1 + bev[q];
            const float pv  = wp[q][0]*pm1 + wp[q][1]*pc + wp[q][2]*pp1 + bpv[q];
            const float xxv = (q ? xv.y : xv.x) + ev + pv;
            cu[q*8 + li] = f2bf(xxv);
            const float dv  = wd[q][0]*dm1 + wd[q][1]*dc + wd[q][2]*dp1 + bdv[q];
            acc[li] += (xxv + dv) * wl[q];
        }
    }
    #pragma unroll
    for (int q = 0; q < 2; ++q) {
        const int d = d0 + q;
        const size_t off = (size_t)b * (NL * ND)
            + (size_t)(((lb >> 5) << 5) + (d >> 4)) * 512
            + (size_t)((((lb >> 3) & 3) << 4) + (d & 15)) * 8;
        *(uint4*)&Xb[off] = chunk[q];
    }

    #pragma unroll
    for (int li = 0; li < 8; ++li)
        #pragma unroll
        for (int off = 32; off; off >>= 1)
            acc[li] += __shfl_down(acc[li], off, 64);
    __shared__ float red[4][8];
    const int lane = tid & 63, wid = tid >> 6;
    if (lane == 0)
        #pragma unroll
        for (int li = 0; li < 8; ++li) red[wid][li] = acc[li];
    __syncthreads();
    if (tid < 8) {
        const float s = red[0][tid] + red[1][tid] + red[2][tid] + red[3][tid] + b_lin[0];
        float r = fmaxf(s, 0.f) + log1pf(expf(-fabsf(s)));
        if (lb + tid >= lens[b]) r = 1.0f;
        ranges[(b << 9) + lb + tid] = r;
    }
}

// ---- Stage 2: means via inclusive scan ----
__global__ __launch_bounds__(512) void means_kernel(
    const int* __restrict__ di, float* __restrict__ means)
{
    const int b = blockIdx.x;
    const int l = threadIdx.x;
    __shared__ int s[NL];
    const int d = di[b * NL + l];
    s[l] = d;
    __syncthreads();
    #pragma unroll
    for (int off = 1; off < NL; off <<= 1) {
        const int v = (l >= off) ? s[l - off] : 0;
        __syncthreads();
        s[l] += v;
        __syncthreads();
    }
    means[b * NL + l] = 0.5f * (float)d + (float)(s[l] - d);
}

// ---- Stage 3: weights f32 output + W' bf16 (fragment layout) ----
__global__ __launch_bounds__(256) void weights2_kernel(
    const float* __restrict__ ranges, const float* __restrict__ means,
    const int* __restrict__ lens,
    float* __restrict__ wout, unsigned short* __restrict__ Wb,
    int T, int MB)
{
    const int b = blockIdx.y;
    const int t = blockIdx.x * 256 + threadIdx.x;
    const int Mpad = MB << 4;
    __shared__ float sm[NL], sinv[NL], sc[NL];
    const int len = lens[b];
    for (int l = threadIdx.x; l < NL; l += 256) {
        const float r = ranges[(b << 9) + l];
        const float inv = 1.f / r;
        sm[l] = means[(b << 9) + l];
        sinv[l] = inv;
        sc[l] = (l < len) ? 0.3989422804014327f * inv : 0.f;
    }
    __syncthreads();
    if (t >= Mpad) return;
    const size_t wbbase = (size_t)b * 16 * MB * 512;
    if (t >= T) {  // zero-fill pad columns so GEMM stages defined data
        const uint4 z = make_uint4(0, 0, 0, 0);
        #pragma unroll 4
        for (int lo = 0; lo < 64; ++lo) {
            const int l = lo << 3;
            const size_t off = wbbase + (size_t)((l >> 5) * MB + (t >> 4)) * 512
                             + (size_t)(((lo & 3) << 4) + (t & 15)) * 8;
            *(uint4*)&Wb[off] = z;
        }
        return;
    }
    const float ft = (float)t + 0.5f;
    float sum = 0.f;
    #pragma unroll 4
    for (int l = 0; l < NL; ++l) {
        const float z = (ft - sm[l]) * sinv[l];
        sum += sc[l] * __expf(-0.5f * z * z);
    }
    const float dinv = 1.f / (sum + 1e-20f);
    for (int l8 = 0; l8 < NL; l8 += 8) {
        uint4 pk;
        unsigned short* pu = (unsigned short*)&pk;
        #pragma unroll
        for (int j = 0; j < 8; ++j) {
            const int l = l8 + j;
            const float z = (ft - sm[l]) * sinv[l];
            const float w = sc[l] * __expf(-0.5f * z * z) * dinv;
            wout[((size_t)(b << 9) + l) * T + t] = w;
            pu[j] = f2bf(w);
        }
        const size_t off = wbbase + (size_t)((l8 >> 5) * MB + (t >> 4)) * 512
                         + (size_t)((((l8 >> 3) & 3) << 4) + (t & 15)) * 8;
        *(uint4*)&Wb[off] = pk;
    }
}

// ---- Stage 4: bf16 MFMA GEMM: O[b][t][d] = sum_l W[l][t] * X[l][d] ----
__global__ __launch_bounds__(256) void gemm_bf16_kernel(
    const unsigned short* __restrict__ Wb,
    const unsigned short* __restrict__ Xb,
    float* __restrict__ out, int T, int MB)
{
    __shared__ __align__(16) char lds[16384];   // A 8KB | B 8KB
    const int b   = blockIdx.z;
    const int my  = blockIdx.y;   // 128-t tile
    const int dx  = blockIdx.x;   // 128-d tile
    const int tid = threadIdx.x;
    const int lane = tid & 63, wid = tid >> 6;
    const int wm = wid >> 1, wn = wid & 1;

    const char* Abase = (const char*)Wb + ((size_t)b * 16 * MB + my * 8) * 1024;
    const char* Bbase = (const char*)Xb + ((size_t)b * 16 * 32 + dx * 8) * 1024;

    f32x4 acc[4][4];
    #pragma unroll
    for (int i = 0; i < 4; ++i)
        #pragma unroll
        for (int j = 0; j < 4; ++j) acc[i][j] = (f32x4){0.f, 0.f, 0.f, 0.f};

    for (int kk = 0; kk < 16; ++kk) {
        __syncthreads();
        const char* As = Abase + (size_t)kk * MB * 1024;
        const char* Bs = Bbase + (size_t)kk * 32 * 1024;
        #pragma unroll
        for (int c = 0; c < 2; ++c) {
            const int ch = wid + c * 4;   // each wave stages 1KB chunks ch for A and B
            __builtin_amdgcn_global_load_lds(
                (__attribute__((address_space(1))) void*)(As + ch * 1024 + lane * 16),
                (__attribute__((address_space(3))) void*)(lds + ch * 1024), 16, 0, 0);
            __builtin_amdgcn_global_load_lds(
                (__attribute__((address_space(1))) void*)(Bs + ch * 1024 + lane * 16),
                (__attribute__((address_space(3))) void*)(lds + 8192 + ch * 1024), 16, 0, 0);
        }
        __syncthreads();
        bf16x8 af[4], bfr[4];
        #pragma unroll
        for (int i = 0; i < 4; ++i)
            af[i] = *(const bf16x8*)(lds + ((wm << 2) + i) * 1024 + lane * 16);
        #pragma unroll
        for (int j = 0; j < 4; ++j)
            bfr[j] = *(const bf16x8*)(lds + 8192 + ((wn << 2) + j) * 1024 + lane * 16);
        #pragma unroll
        for (int i = 0; i < 4; ++i)
            #pragma unroll
            for (int j = 0; j < 4; ++j)
                acc[i][j] = __builtin_amdgcn_mfma_f32_16x16x32_bf16(af[i], bfr[j], acc[i][j], 0, 0, 0);
    }

    const int t_base = my * 128 + wm * 64;
    const int d_base = dx * 128 + wn * 64 + (lane & 15);
    float* Ob = out + (size_t)b * T * ND;
    #pragma unroll
    for (int i = 0; i < 4; ++i) {
        #pragma unroll
        for (int r = 0; r < 4; ++r) {
            const int t = t_base + i * 16 + ((lane >> 4) << 2) + r;
            if (t < T) {
                #pragma unroll
                for (int j = 0; j < 4; ++j)
                    Ob[(size_t)t * ND + d_base + j * 16] = acc[i][j][r];
            }
        }
    }
}

// ============================================================================
// FALLBACK PATH (round-1 f32, used only if ws_size too small)
// ============================================================================
__global__ __launch_bounds__(256) void fuse_kernel(
    const float* __restrict__ x, const float* __restrict__ df,
    const float* __restrict__ en, const float* __restrict__ pi,
    const int* __restrict__ lens,
    const float* __restrict__ w_dur, const float* __restrict__ b_dur,
    const float* __restrict__ w_en,  const float* __restrict__ b_en,
    const float* __restrict__ w_pi,  const float* __restrict__ b_pi,
    const float* __restrict__ w_lin, const float* __restrict__ b_lin,
    float* __restrict__ xx, float* __restrict__ ranges)
{
    const int bl = blockIdx.x;
    const int b  = bl >> 9;
    const int l  = bl & (NL - 1);
    const int tid = threadIdx.x;
    const float dm1 = (l > 0)      ? df[bl - 1] : 0.f;
    const float d0  = df[bl];
    const float dp1 = (l < NL - 1) ? df[bl + 1] : 0.f;
    const float em1 = (l > 0)      ? en[bl - 1] : 0.f;
    const float e0  = en[bl];
    const float ep1 = (l < NL - 1) ? en[bl + 1] : 0.f;
    const float pm1 = (l > 0)      ? pi[bl - 1] : 0.f;
    const float p0  = pi[bl];
    const float pp1 = (l < NL - 1) ? pi[bl + 1] : 0.f;
    float acc = 0.f;
    #pragma unroll
    for (int d = tid; d < ND; d += 256) {
        const float xv = x[(size_t)bl * ND + d];
        const float ev = w_en[d*3]*em1 + w_en[d*3+1]*e0 + w_en[d*3+2]*ep1 + b_en[d];
        const float pv = w_pi[d*3]*pm1 + w_pi[d*3+1]*p0 + w_pi[d*3+2]*pp1 + b_pi[d];
        const float xxv = xv + ev + pv;
        xx[(size_t)bl * ND + d] = xxv;
        const float dv = w_dur[d*3]*dm1 + w_dur[d*3+1]*d0 + w_dur[d*3+2]*dp1 + b_dur[d];
        acc += (xxv + dv) * w_lin[d];
    }
    #pragma unroll
    for (int off = 32; off; off >>= 1) acc += __shfl_down(acc, off, 64);
    __shared__ float red[4];
    const int lane = tid & 63, wid = tid >> 6;
    if (lane == 0) red[wid] = acc;
    __syncthreads();
    if (tid == 0) {
        const float s = red[0] + red[1] + red[2] + red[3] + b_lin[0];
        float r = fmaxf(s, 0.f) + log1pf(expf(-fabsf(s)));
        if (l >= lens[b]) r = 1.0f;
        ranges[bl] = r;
    }
}

__global__ __launch_bounds__(256) void weights_kernel(
    const float* __restrict__ ranges, const float* __restrict__ means,
    const int* __restrict__ lens, float* __restrict__ weights, int T)
{
    const int b = blockIdx.y;
    const int t = blockIdx.x * 256 + threadIdx.x;
    __shared__ float sm[NL], sinv[NL], sc[NL];
    const int len = lens[b];
    for (int l = threadIdx.x; l < NL; l += 256) {
        const float r = ranges[b * NL + l];
        const float inv = 1.f / r;
        sm[l] = means[b * NL + l];
        sinv[l] = inv;
        sc[l] = (l < len) ? 0.3989422804014327f * inv : 0.f;
    }
    __syncthreads();
    if (t >= T) return;
    const float ft = (float)t + 0.5f;
    float sum = 0.f;
    #pragma unroll 4
    for (int l = 0; l < NL; ++l) {
        const float z = (ft - sm[l]) * sinv[l];
        sum += sc[l] * __expf(-0.5f * z * z);
    }
    const float dinv = 1.f / (sum + 1e-20f);
    #pragma unroll 4
    for (int l = 0; l < NL; ++l) {
        const float z = (ft - sm[l]) * sinv[l];
        weights[((size_t)b * NL + l) * T + t] = sc[l] * __expf(-0.5f * z * z) * dinv;
    }
}

#define BM 64
#define BN 64
#define BK 16
__global__ __launch_bounds__(256) void gemm_f32_kernel(
    const float* __restrict__ xx, const float* __restrict__ weights,
    float* __restrict__ out, int T)
{
    const int b  = blockIdx.z;
    const int t0 = blockIdx.y * BM;
    const int d0 = blockIdx.x * BN;
    const float* __restrict__ W = weights + (size_t)b * NL * T;
    const float* __restrict__ X = xx + (size_t)b * NL * ND;
    float* __restrict__ O = out + (size_t)b * T * ND;
    __shared__ float As[BK][BM];
    __shared__ float Bs[BK][BN];
    const int tid = threadIdx.x;
    const int tx = tid & 15;
    const int ty = tid >> 4;
    const int lr = tid >> 4;
    const int lc = (tid & 15) * 4;
    const bool vec_ok = (t0 + BM <= T) && ((T & 3) == 0);
    float acc[4][4] = {};
    for (int l0 = 0; l0 < NL; l0 += BK) {
        if (vec_ok) {
            *(float4*)&As[lr][lc] = *(const float4*)&W[(size_t)(l0 + lr) * T + t0 + lc];
        } else {
            #pragma unroll
            for (int j = 0; j < 4; ++j) {
                const int tcol = t0 + lc + j;
                As[lr][lc + j] = (tcol < T) ? W[(size_t)(l0 + lr) * T + tcol] : 0.f;
            }
        }
        *(float4*)&Bs[lr][lc] = *(const float4*)&X[(size_t)(l0 + lr) * ND + d0 + lc];
        __syncthreads();
        #pragma unroll
        for (int k = 0; k < BK; ++k) {
            float a[4], bb[4];
            *(float4*)a  = *(const float4*)&As[k][ty * 4];
            *(float4*)bb = *(const float4*)&Bs[k][tx * 4];
            #pragma unroll
            for (int i = 0; i < 4; ++i)
                #pragma unroll
                for (int j = 0; j < 4; ++j)
                    acc[i][j] += a[i] * bb[j];
        }
        __syncthreads();
    }
    #pragma unroll
    for (int i = 0; i < 4; ++i) {
        const int t = t0 + ty * 4 + i;
        if (t < T)
            *(float4*)&O[(size_t)t * ND + d0 + tx * 4] =
                make_float4(acc[i][0], acc[i][1], acc[i][2], acc[i][3]);
    }
}

// ============================================================================
extern "C" void kernel_launch(void* const* d_in, const int* in_sizes, int n_in,
                              void* d_out, int out_size, void* d_ws, size_t ws_size,
                              hipStream_t stream) {
    const float* x     = (const float*)d_in[0];
    const float* df    = (const float*)d_in[1];
    const int*   di    = (const int*)  d_in[2];
    const float* en    = (const float*)d_in[3];
    const float* pi    = (const float*)d_in[4];
    const int*   lens  = (const int*)  d_in[5];
    const float* w_dur = (const float*)d_in[6];
    const float* b_dur = (const float*)d_in[7];
    const float* w_en  = (const float*)d_in[8];
    const float* b_en  = (const float*)d_in[9];
    const float* w_pi  = (const float*)d_in[10];
    const float* b_pi  = (const float*)d_in[11];
    const float* w_lin = (const float*)d_in[12];
    const float* b_lin = (const float*)d_in[13];

    const int B = NB, L = NL, D = ND;
    const int T = out_size / (B * (L + D));
    const int Mpad = ((T + 127) / 128) * 128;
    const int MB = Mpad >> 4;

    float* xup  = (float*)d_out;                 // (B,T,D)
    float* wout = xup + (size_t)B * T * D;       // (B,L,T)

    const size_t XbBytes = (size_t)B * L * D * 2;
    const size_t WbBytes = (size_t)B * Mpad * 512 * 2;
    const size_t need = XbBytes + WbBytes + 2 * (size_t)B * L * sizeof(float);

    if (ws_size >= need) {
        unsigned short* Xb = (unsigned short*)d_ws;
        unsigned short* Wb = Xb + (size_t)B * L * D;
        float* ranges = (float*)(Wb + (size_t)B * Mpad * 512);
        float* means  = ranges + B * L;

        hipLaunchKernelGGL(fuse2_kernel, dim3(B * 64), dim3(256), 0, stream,
                           x, df, en, pi, lens, w_dur, b_dur, w_en, b_en,
                           w_pi, b_pi, w_lin, b_lin, Xb, ranges);
        hipLaunchKernelGGL(means_kernel, dim3(B), dim3(512), 0, stream, di, means);
        hipLaunchKernelGGL(weights2_kernel, dim3((Mpad + 255) / 256, B), dim3(256), 0, stream,
                           ranges, means, lens, wout, Wb, T, MB);
        hipLaunchKernelGGL(gemm_bf16_kernel, dim3(4, Mpad / 128, B), dim3(256), 0, stream,
                           Wb, Xb, xup, T, MB);
    } else {
        float* xx     = (float*)d_ws;
        float* ranges = xx + (size_t)B * L * D;
        float* means  = ranges + (size_t)B * L;
        hipLaunchKernelGGL(fuse_kernel, dim3(B * L), dim3(256), 0, stream,
                           x, df, en, pi, lens, w_dur, b_dur, w_en, b_en,
                           w_pi, b_pi, w_lin, b_lin, xx, ranges);
        hipLaunchKernelGGL(means_kernel, dim3(B), dim3(512), 0, stream, di, means);
        hipLaunchKernelGGL(weights_kernel, dim3((T + 255) / 256, B), dim3(256), 0, stream,
                           ranges, means, lens, wout, T);
        hipLaunchKernelGGL(gemm_f32_kernel, dim3(D / BN, (T + BM - 1) / BM, B), dim3(256), 0, stream,
                           xx, wout, xup, T);
    }
}

// Round 3
// 139.842 us; speedup vs baseline: 3.4455x; 1.1976x over previous
//
#include <hip/hip_runtime.h>
#include <hip/hip_bf16.h>
#include <stdint.h>

#define NB 32
#define NL 512
#define ND 512

typedef __bf16 bf16x8 __attribute__((ext_vector_type(8)));
typedef float  f32x4  __attribute__((ext_vector_type(4)));

__device__ __forceinline__ unsigned short f2bf(float f) {
    uint32_t u = __float_as_uint(f);
    u = (u + 0x7fffu + ((u >> 16) & 1u)) >> 16;
    return (unsigned short)u;
}

// ============================================================================
// FAST PATH
// X' layout (per batch): [kk=l>>5][db=d>>4] subtiles of 512 bf16:
//   subtile chunk c=0..63 (16B) holds (k=(c>>4)*8+j, n=c&15): X[l=kk*32+k][d=db*16+n]
// W' layout (per batch): [kk=l>>5][mb=t>>4] subtiles, same element scheme.
// Both match mfma_f32_16x16x32_bf16 A/B lane layout, so the GEMM stages with
// linear global_load_lds and reads fragments lane-linearly (conflict-free).
// ============================================================================

// ---- Stage 1: fused convs -> X' bf16 (fragment layout) + ranges ----
__global__ __launch_bounds__(256) void fuse2_kernel(
    const float* __restrict__ x, const float* __restrict__ df,
    const float* __restrict__ en, const float* __restrict__ pi,
    const int* __restrict__ lens,
    const float* __restrict__ w_dur, const float* __restrict__ b_dur,
    const float* __restrict__ w_en,  const float* __restrict__ b_en,
    const float* __restrict__ w_pi,  const float* __restrict__ b_pi,
    const float* __restrict__ w_lin, const float* __restrict__ b_lin,
    unsigned short* __restrict__ Xb, float* __restrict__ ranges)
{
    const int blk = blockIdx.x;          // B * 64
    const int b   = blk >> 6;
    const int lb  = (blk & 63) << 3;     // 8 consecutive l
    const int tid = threadIdx.x;
    const int d0  = tid << 1;            // 2 consecutive d

    float we[2][3], wp[2][3], wd[2][3], bev[2], bpv[2], bdv[2], wl[2];
    #pragma unroll
    for (int q = 0; q < 2; ++q) {
        const int d = d0 + q;
        #pragma unroll
        for (int k = 0; k < 3; ++k) {
            we[q][k] = w_en[d*3+k];
            wp[q][k] = w_pi[d*3+k];
            wd[q][k] = w_dur[d*3+k];
        }
        bev[q] = b_en[d]; bpv[q] = b_pi[d]; bdv[q] = b_dur[d]; wl[q] = w_lin[d];
    }

    float acc[8];
    #pragma unroll
    for (int i = 0; i < 8; ++i) acc[i] = 0.f;

    uint4 chunk[2];
    unsigned short* cu = (unsigned short*)chunk;

    #pragma unroll
    for (int li = 0; li < 8; ++li) {
        const int l  = lb + li;
        const int bl = (b << 9) + l;
        const float dm1 = (l > 0)      ? df[bl-1] : 0.f;
        const float dc  = df[bl];
        const float dp1 = (l < NL-1)   ? df[bl+1] : 0.f;
        const float em1 = (l > 0)      ? en[bl-1] : 0.f;
        const float ec  = en[bl];
        const float ep1 = (l < NL-1)   ? en[bl+1] : 0.f;
        const float pm1 = (l > 0)      ? pi[bl-1] : 0.f;
        const float pc  = pi[bl];
        const float pp1 = (l < NL-1)   ? pi[bl+1] : 0.f;
        const float2 xv = *(const float2*)&x[(size_t)bl * ND + d0];
        #pragma unroll
        for (int q = 0; q < 2; ++q) {
            const float ev  = we[q][0]*em1 + we[q][1]*ec + we[q][2]*ep1 + bev[q];
            const float pv  = wp[q][0]*pm1 + wp[q][1]*pc + wp[q][2]*pp1 + bpv[q];
            const float xxv = (q ? xv.y : xv.x) + ev + pv;
            cu[q*8 + li] = f2bf(xxv);
            const float dv  = wd[q][0]*dm1 + wd[q][1]*dc + wd[q][2]*dp1 + bdv[q];
            acc[li] += (xxv + dv) * wl[q];
        }
    }
    #pragma unroll
    for (int q = 0; q < 2; ++q) {
        const int d = d0 + q;
        const size_t off = (size_t)b * (NL * ND)
            + (size_t)(((lb >> 5) << 5) + (d >> 4)) * 512
            + (size_t)((((lb >> 3) & 3) << 4) + (d & 15)) * 8;
        *(uint4*)&Xb[off] = chunk[q];
    }

    #pragma unroll
    for (int li = 0; li < 8; ++li)
        #pragma unroll
        for (int off = 32; off; off >>= 1)
            acc[li] += __shfl_down(acc[li], off, 64);
    __shared__ float red[4][8];
    const int lane = tid & 63, wid = tid >> 6;
    if (lane == 0)
        #pragma unroll
        for (int li = 0; li < 8; ++li) red[wid][li] = acc[li];
    __syncthreads();
    if (tid < 8) {
        const float s = red[0][tid] + red[1][tid] + red[2][tid] + red[3][tid] + b_lin[0];
        float r = fmaxf(s, 0.f) + log1pf(expf(-fabsf(s)));
        if (lb + tid >= lens[b]) r = 1.0f;
        ranges[(b << 9) + lb + tid] = r;
    }
}

// ---- Stage 2: means via inclusive scan ----
__global__ __launch_bounds__(512) void means_kernel(
    const int* __restrict__ di, float* __restrict__ means)
{
    const int b = blockIdx.x;
    const int l = threadIdx.x;
    __shared__ int s[NL];
    const int d = di[b * NL + l];
    s[l] = d;
    __syncthreads();
    #pragma unroll
    for (int off = 1; off < NL; off <<= 1) {
        const int v = (l >= off) ? s[l - off] : 0;
        __syncthreads();
        s[l] += v;
        __syncthreads();
    }
    means[b * NL + l] = 0.5f * (float)d + (float)(s[l] - d);
}

// ---- Stage 3: weights f32 output + W' bf16 (fragment layout) ----
__global__ __launch_bounds__(256) void weights2_kernel(
    const float* __restrict__ ranges, const float* __restrict__ means,
    const int* __restrict__ lens,
    float* __restrict__ wout, unsigned short* __restrict__ Wb,
    int T, int MB)
{
    const int b = blockIdx.y;
    const int t = blockIdx.x * 256 + threadIdx.x;
    const int Mpad = MB << 4;
    __shared__ float sm[NL], sinv[NL], sc[NL];
    const int len = lens[b];
    for (int l = threadIdx.x; l < NL; l += 256) {
        const float r = ranges[(b << 9) + l];
        const float inv = 1.f / r;
        sm[l] = means[(b << 9) + l];
        sinv[l] = inv;
        sc[l] = (l < len) ? 0.3989422804014327f * inv : 0.f;
    }
    __syncthreads();
    if (t >= Mpad) return;
    const size_t wbbase = (size_t)b * 16 * MB * 512;
    if (t >= T) {  // zero-fill pad columns so GEMM stages defined data
        const uint4 z = make_uint4(0, 0, 0, 0);
        #pragma unroll 4
        for (int lo = 0; lo < 64; ++lo) {
            const int l = lo << 3;
            const size_t off = wbbase + (size_t)((l >> 5) * MB + (t >> 4)) * 512
                             + (size_t)(((lo & 3) << 4) + (t & 15)) * 8;
            *(uint4*)&Wb[off] = z;
        }
        return;
    }
    const float ft = (float)t + 0.5f;
    float sum = 0.f;
    #pragma unroll 4
    for (int l = 0; l < NL; ++l) {
        const float z = (ft - sm[l]) * sinv[l];
        sum += sc[l] * __expf(-0.5f * z * z);
    }
    const float dinv = 1.f / (sum + 1e-20f);
    for (int l8 = 0; l8 < NL; l8 += 8) {
        uint4 pk;
        unsigned short* pu = (unsigned short*)&pk;
        #pragma unroll
        for (int j = 0; j < 8; ++j) {
            const int l = l8 + j;
            const float z = (ft - sm[l]) * sinv[l];
            const float w = sc[l] * __expf(-0.5f * z * z) * dinv;
            wout[((size_t)(b << 9) + l) * T + t] = w;
            pu[j] = f2bf(w);
        }
        const size_t off = wbbase + (size_t)((l8 >> 5) * MB + (t >> 4)) * 512
                         + (size_t)((((l8 >> 3) & 3) << 4) + (t & 15)) * 8;
        *(uint4*)&Wb[off] = pk;
    }
}

// ---- Stage 4: bf16 MFMA GEMM with dbuf prefetch + XCD-group swizzle ----
// O[b][t][d] = sum_l W[l][t] * X[l][d]
// Work decomposition: group g = m*32 + b (one 128-t A panel), 4 n-works each.
// hw block i: xcd = i&7, slot = i>>3, g = (slot>>2)*8 + xcd, n = slot&3.
// All 4 n-works of a group land on one XCD; per XCD only b ≡ xcd (mod 8)
// appears, so the Xb panels it touches (4 batches * 512KB/4) stay L2-resident.
#define STAGE(kk, buf) do {                                                     \
    const char* As_ = Abase + (size_t)(kk) * MB * 1024;                         \
    const char* Bs_ = Bbase + (size_t)(kk) * 32768;                             \
    char* dst_ = lds + (buf) * 16384;                                           \
    _Pragma("unroll")                                                           \
    for (int c = 0; c < 2; ++c) {                                               \
        const int ch = wid * 2 + c;                                             \
        __builtin_amdgcn_global_load_lds(                                       \
            (__attribute__((address_space(1))) void*)(As_ + ch * 1024 + lane * 16), \
            (__attribute__((address_space(3))) void*)(dst_ + ch * 1024), 16, 0, 0); \
        __builtin_amdgcn_global_load_lds(                                       \
            (__attribute__((address_space(1))) void*)(Bs_ + ch * 1024 + lane * 16), \
            (__attribute__((address_space(3))) void*)(dst_ + 8192 + ch * 1024), 16, 0, 0); \
    }                                                                           \
} while (0)

__global__ __launch_bounds__(256) void gemm_bf16_kernel(
    const unsigned short* __restrict__ Wb,
    const unsigned short* __restrict__ Xb,
    float* __restrict__ out, int T, int MB)
{
    __shared__ __align__(16) char lds[32768];   // 2 bufs x (A 8KB | B 8KB)
    const int tid  = threadIdx.x;
    const int lane = tid & 63, wid = tid >> 6;
    const int wm = wid >> 1, wn = wid & 1;

    const int i    = blockIdx.x;
    const int xcd  = i & 7, slot = i >> 3;
    const int g    = ((slot >> 2) << 3) + xcd;  // group in [0, MT*32)
    const int n    = slot & 3;                  // 128-d tile
    const int m    = g >> 5;                    // 128-t tile
    const int b    = g & 31;

    const char* Abase = (const char*)Wb + ((size_t)b * 16 * MB + m * 8) * 1024;
    const char* Bbase = (const char*)Xb + ((size_t)b * 512 + n * 8) * 1024;

    f32x4 acc[4][4];
    #pragma unroll
    for (int ii = 0; ii < 4; ++ii)
        #pragma unroll
        for (int jj = 0; jj < 4; ++jj) acc[ii][jj] = (f32x4){0.f, 0.f, 0.f, 0.f};

    STAGE(0, 0);

    #pragma unroll 2
    for (int kk = 0; kk < 16; ++kk) {
        const int cur = kk & 1;
        __syncthreads();                 // drains vmcnt: buf[cur] ready
        if (kk < 15) STAGE(kk + 1, cur ^ 1);   // prefetch overlaps MFMA below
        const char* bufp = lds + cur * 16384;
        bf16x8 af[4], bfr[4];
        #pragma unroll
        for (int ii = 0; ii < 4; ++ii)
            af[ii] = *(const bf16x8*)(bufp + ((wm << 2) + ii) * 1024 + lane * 16);
        #pragma unroll
        for (int jj = 0; jj < 4; ++jj)
            bfr[jj] = *(const bf16x8*)(bufp + 8192 + ((wn << 2) + jj) * 1024 + lane * 16);
        #pragma unroll
        for (int ii = 0; ii < 4; ++ii)
            #pragma unroll
            for (int jj = 0; jj < 4; ++jj)
                acc[ii][jj] = __builtin_amdgcn_mfma_f32_16x16x32_bf16(af[ii], bfr[jj], acc[ii][jj], 0, 0, 0);
    }

    const int t_base = m * 128 + wm * 64;
    const int d_base = n * 128 + wn * 64 + (lane & 15);
    float* Ob = out + (size_t)b * T * ND;
    #pragma unroll
    for (int ii = 0; ii < 4; ++ii) {
        #pragma unroll
        for (int r = 0; r < 4; ++r) {
            const int t = t_base + ii * 16 + ((lane >> 4) << 2) + r;
            if (t < T) {
                #pragma unroll
                for (int jj = 0; jj < 4; ++jj)
                    Ob[(size_t)t * ND + d_base + jj * 16] = acc[ii][jj][r];
            }
        }
    }
}

// ============================================================================
// FALLBACK PATH (round-1 f32, used only if ws_size too small)
// ============================================================================
__global__ __launch_bounds__(256) void fuse_kernel(
    const float* __restrict__ x, const float* __restrict__ df,
    const float* __restrict__ en, const float* __restrict__ pi,
    const int* __restrict__ lens,
    const float* __restrict__ w_dur, const float* __restrict__ b_dur,
    const float* __restrict__ w_en,  const float* __restrict__ b_en,
    const float* __restrict__ w_pi,  const float* __restrict__ b_pi,
    const float* __restrict__ w_lin, const float* __restrict__ b_lin,
    float* __restrict__ xx, float* __restrict__ ranges)
{
    const int bl = blockIdx.x;
    const int b  = bl >> 9;
    const int l  = bl & (NL - 1);
    const int tid = threadIdx.x;
    const float dm1 = (l > 0)      ? df[bl - 1] : 0.f;
    const float d0  = df[bl];
    const float dp1 = (l < NL - 1) ? df[bl + 1] : 0.f;
    const float em1 = (l > 0)      ? en[bl - 1] : 0.f;
    const float e0  = en[bl];
    const float ep1 = (l < NL - 1) ? en[bl + 1] : 0.f;
    const float pm1 = (l > 0)      ? pi[bl - 1] : 0.f;
    const float p0  = pi[bl];
    const float pp1 = (l < NL - 1) ? pi[bl + 1] : 0.f;
    float acc = 0.f;
    #pragma unroll
    for (int d = tid; d < ND; d += 256) {
        const float xv = x[(size_t)bl * ND + d];
        const float ev = w_en[d*3]*em1 + w_en[d*3+1]*e0 + w_en[d*3+2]*ep1 + b_en[d];
        const float pv = w_pi[d*3]*pm1 + w_pi[d*3+1]*p0 + w_pi[d*3+2]*pp1 + b_pi[d];
        const float xxv = xv + ev + pv;
        xx[(size_t)bl * ND + d] = xxv;
        const float dv = w_dur[d*3]*dm1 + w_dur[d*3+1]*d0 + w_dur[d*3+2]*dp1 + b_dur[d];
        acc += (xxv + dv) * w_lin[d];
    }
    #pragma unroll
    for (int off = 32; off; off >>= 1) acc += __shfl_down(acc, off, 64);
    __shared__ float red[4];
    const int lane = tid & 63, wid = tid >> 6;
    if (lane == 0) red[wid] = acc;
    __syncthreads();
    if (tid == 0) {
        const float s = red[0] + red[1] + red[2] + red[3] + b_lin[0];
        float r = fmaxf(s, 0.f) + log1pf(expf(-fabsf(s)));
        if (l >= lens[b]) r = 1.0f;
        ranges[bl] = r;
    }
}

__global__ __launch_bounds__(256) void weights_kernel(
    const float* __restrict__ ranges, const float* __restrict__ means,
    const int* __restrict__ lens, float* __restrict__ weights, int T)
{
    const int b = blockIdx.y;
    const int t = blockIdx.x * 256 + threadIdx.x;
    __shared__ float sm[NL], sinv[NL], sc[NL];
    const int len = lens[b];
    for (int l = threadIdx.x; l < NL; l += 256) {
        const float r = ranges[b * NL + l];
        const float inv = 1.f / r;
        sm[l] = means[b * NL + l];
        sinv[l] = inv;
        sc[l] = (l < len) ? 0.3989422804014327f * inv : 0.f;
    }
    __syncthreads();
    if (t >= T) return;
    const float ft = (float)t + 0.5f;
    float sum = 0.f;
    #pragma unroll 4
    for (int l = 0; l < NL; ++l) {
        const float z = (ft - sm[l]) * sinv[l];
        sum += sc[l] * __expf(-0.5f * z * z);
    }
    const float dinv = 1.f / (sum + 1e-20f);
    #pragma unroll 4
    for (int l = 0; l < NL; ++l) {
        const float z = (ft - sm[l]) * sinv[l];
        weights[((size_t)b * NL + l) * T + t] = sc[l] * __expf(-0.5f * z * z) * dinv;
    }
}

#define BM 64
#define BN 64
#define BK 16
__global__ __launch_bounds__(256) void gemm_f32_kernel(
    const float* __restrict__ xx, const float* __restrict__ weights,
    float* __restrict__ out, int T)
{
    const int b  = blockIdx.z;
    const int t0 = blockIdx.y * BM;
    const int d0 = blockIdx.x * BN;
    const float* __restrict__ W = weights + (size_t)b * NL * T;
    const float* __restrict__ X = xx + (size_t)b * NL * ND;
    float* __restrict__ O = out + (size_t)b * T * ND;
    __shared__ float As[BK][BM];
    __shared__ float Bs[BK][BN];
    const int tid = threadIdx.x;
    const int tx = tid & 15;
    const int ty = tid >> 4;
    const int lr = tid >> 4;
    const int lc = (tid & 15) * 4;
    const bool vec_ok = (t0 + BM <= T) && ((T & 3) == 0);
    float acc[4][4] = {};
    for (int l0 = 0; l0 < NL; l0 += BK) {
        if (vec_ok) {
            *(float4*)&As[lr][lc] = *(const float4*)&W[(size_t)(l0 + lr) * T + t0 + lc];
        } else {
            #pragma unroll
            for (int j = 0; j < 4; ++j) {
                const int tcol = t0 + lc + j;
                As[lr][lc + j] = (tcol < T) ? W[(size_t)(l0 + lr) * T + tcol] : 0.f;
            }
        }
        *(float4*)&Bs[lr][lc] = *(const float4*)&X[(size_t)(l0 + lr) * ND + d0 + lc];
        __syncthreads();
        #pragma unroll
        for (int k = 0; k < BK; ++k) {
            float a[4], bb[4];
            *(float4*)a  = *(const float4*)&As[k][ty * 4];
            *(float4*)bb = *(const float4*)&Bs[k][tx * 4];
            #pragma unroll
            for (int i = 0; i < 4; ++i)
                #pragma unroll
                for (int j = 0; j < 4; ++j)
                    acc[i][j] += a[i] * bb[j];
        }
        __syncthreads();
    }
    #pragma unroll
    for (int i = 0; i < 4; ++i) {
        const int t = t0 + ty * 4 + i;
        if (t < T)
            *(float4*)&O[(size_t)t * ND + d0 + tx * 4] =
                make_float4(acc[i][0], acc[i][1], acc[i][2], acc[i][3]);
    }
}

// ============================================================================
extern "C" void kernel_launch(void* const* d_in, const int* in_sizes, int n_in,
                              void* d_out, int out_size, void* d_ws, size_t ws_size,
                              hipStream_t stream) {
    const float* x     = (const float*)d_in[0];
    const float* df    = (const float*)d_in[1];
    const int*   di    = (const int*)  d_in[2];
    const float* en    = (const float*)d_in[3];
    const float* pi    = (const float*)d_in[4];
    const int*   lens  = (const int*)  d_in[5];
    const float* w_dur = (const float*)d_in[6];
    const float* b_dur = (const float*)d_in[7];
    const float* w_en  = (const float*)d_in[8];
    const float* b_en  = (const float*)d_in[9];
    const float* w_pi  = (const float*)d_in[10];
    const float* b_pi  = (const float*)d_in[11];
    const float* w_lin = (const float*)d_in[12];
    const float* b_lin = (const float*)d_in[13];

    const int B = NB, L = NL, D = ND;
    const int T = out_size / (B * (L + D));
    const int Mpad = ((T + 127) / 128) * 128;
    const int MB = Mpad >> 4;
    const int MT = Mpad >> 7;

    float* xup  = (float*)d_out;                 // (B,T,D)
    float* wout = xup + (size_t)B * T * D;       // (B,L,T)

    const size_t XbBytes = (size_t)B * L * D * 2;
    const size_t WbBytes = (size_t)B * Mpad * 512 * 2;
    const size_t need = XbBytes + WbBytes + 2 * (size_t)B * L * sizeof(float);

    if (ws_size >= need) {
        unsigned short* Xb = (unsigned short*)d_ws;
        unsigned short* Wb = Xb + (size_t)B * L * D;
        float* ranges = (float*)(Wb + (size_t)B * Mpad * 512);
        float* means  = ranges + B * L;

        hipLaunchKernelGGL(fuse2_kernel, dim3(B * 64), dim3(256), 0, stream,
                           x, df, en, pi, lens, w_dur, b_dur, w_en, b_en,
                           w_pi, b_pi, w_lin, b_lin, Xb, ranges);
        hipLaunchKernelGGL(means_kernel, dim3(B), dim3(512), 0, stream, di, means);
        hipLaunchKernelGGL(weights2_kernel, dim3((Mpad + 255) / 256, B), dim3(256), 0, stream,
                           ranges, means, lens, wout, Wb, T, MB);
        hipLaunchKernelGGL(gemm_bf16_kernel, dim3(MT * 128), dim3(256), 0, stream,
                           Wb, Xb, xup, T, MB);
    } else {
        float* xx     = (float*)d_ws;
        float* ranges = xx + (size_t)B * L * D;
        float* means  = ranges + (size_t)B * L;
        hipLaunchKernelGGL(fuse_kernel, dim3(B * L), dim3(256), 0, stream,
                           x, df, en, pi, lens, w_dur, b_dur, w_en, b_en,
                           w_pi, b_pi, w_lin, b_lin, xx, ranges);
        hipLaunchKernelGGL(means_kernel, dim3(B), dim3(512), 0, stream, di, means);
        hipLaunchKernelGGL(weights_kernel, dim3((T + 255) / 256, B), dim3(256), 0, stream,
                           ranges, means, lens, wout, T);
        hipLaunchKernelGGL(gemm_f32_kernel, dim3(D / BN, (T + BM - 1) / BM, B), dim3(256), 0, stream,
                           xx, wout, xup, T);
    }
}